// Round 1
// baseline (5220.049 us; speedup 1.0000x reference)
//
#include <hip/hip_runtime.h>
#include <math.h>

// KMeansGrouping: B=32 batches, N=4096 points, D=256 dims, K=24 slots, 25 iters.
// Strategy: match the numpy-f64 reference trajectory exactly (chaotic argmin chain)
// by doing all distance / center arithmetic in f64 with deterministic fixed-order
// reductions. x is never materialized: x[n,d] = feat[n,d] * inv_norm[n] (f64).
// argmin uses score = c_sq[k] - 2*(dot(feat,c_k)*inv) -- x_sq is k-uniform, dropped.

#define BATCH 32
#define NPTS 4096
#define DIM 256
#define NSLOT 24
#define NITER 25
#define NCHUNK 16
#define PTS 256 // NPTS / NCHUNK, == blockDim (thread-per-point in phase 1)

// ---------------- K0: per-point inverse norm (f64) ----------------
__global__ __launch_bounds__(256) void k_norm(const float* __restrict__ feat,
                                              double* __restrict__ inv_norm) {
  int lane = threadIdx.x & 63;
  int wid = threadIdx.x >> 6;
  int p = blockIdx.x * 4 + wid; // one wave per point
  const float4 v = *(const float4*)(feat + (size_t)p * DIM + lane * 4);
  double s = (double)v.x * v.x + (double)v.y * v.y + (double)v.z * v.z + (double)v.w * v.w;
#pragma unroll
  for (int m = 32; m; m >>= 1) s += __shfl_xor(s, m);
  if (lane == 0) inv_norm[p] = 1.0 / fmax(sqrt(s), 1e-12);
}

__device__ __forceinline__ double block_sum_256(double v, double* red) {
#pragma unroll
  for (int m = 32; m; m >>= 1) v += __shfl_xor(v, m);
  int w = threadIdx.x >> 6;
  if ((threadIdx.x & 63) == 0) red[w] = v;
  __syncthreads();
  return red[0] + red[1] + red[2] + red[3];
}

// ---------------- K0b: initial centers + c_sq ----------------
// init_idx = floor(linspace(0, N-1, K)) with numpy endpoint semantics:
// idx_k = floor(k*4095/23) = 178*k for k<23, 4095 for k=23.
__global__ __launch_bounds__(256) void k_init_centers(const float* __restrict__ feat,
                                                      const double* __restrict__ inv_norm,
                                                      double* __restrict__ centers,
                                                      double* __restrict__ c_sq) {
  __shared__ double red[4];
  int t = threadIdx.x, k = blockIdx.x, b = blockIdx.y;
  int idx = (int)((double)k * (NPTS - 1) / (NSLOT - 1));
  double v = (double)feat[((size_t)b * NPTS + idx) * DIM + t] * inv_norm[b * NPTS + idx];
  centers[((size_t)b * NSLOT + k) * DIM + t] = v;
  double s = block_sum_256(v * v, red);
  if (t == 0) c_sq[b * NSLOT + k] = s;
}

// ---------------- K1: fused assign + partial center sums ----------------
#define CASE_ACC(i) \
  case i: acc[i] += xv; ++cnt[i]; break;

__global__ __launch_bounds__(256, 2) void k_iter(const float* __restrict__ feat,
                                                 const double* __restrict__ inv_norm,
                                                 const double* __restrict__ centers,
                                                 const double* __restrict__ c_sq,
                                                 double* __restrict__ psums,
                                                 int* __restrict__ pcnts,
                                                 float* __restrict__ masks_out,
                                                 float* __restrict__ centers_out,
                                                 int final_pass) {
  __shared__ double c_lds[NSLOT * DIM]; // 49152 B
  __shared__ double csq_lds[NSLOT];
  __shared__ int assign_lds[PTS];
  int t = threadIdx.x, ch = blockIdx.x, b = blockIdx.y;

  const double* cb = centers + (size_t)b * NSLOT * DIM;
#pragma unroll
  for (int i = 0; i < NSLOT; ++i) c_lds[i * DIM + t] = cb[i * DIM + t];
  if (t < NSLOT) csq_lds[t] = c_sq[b * NSLOT + t];
  __syncthreads();

  // ---- phase 1: thread-per-point distance + argmin ----
  int n = ch * PTS + t;
  const float* xp = feat + ((size_t)b * NPTS + n) * DIM;
  double inv = inv_norm[b * NPTS + n];

  double dot[NSLOT];
#pragma unroll
  for (int k = 0; k < NSLOT; ++k) dot[k] = 0.0;

  for (int db = 0; db < DIM / 32; ++db) { // 8 blocks of 32 dims
    double xd[32];
#pragma unroll
    for (int j = 0; j < 8; ++j) {
      float4 v = *(const float4*)(xp + db * 32 + j * 4);
      xd[j * 4 + 0] = v.x;
      xd[j * 4 + 1] = v.y;
      xd[j * 4 + 2] = v.z;
      xd[j * 4 + 3] = v.w;
    }
#pragma unroll
    for (int k = 0; k < NSLOT; ++k) {
      const double* cp = &c_lds[k * DIM + db * 32];
      double s = dot[k];
#pragma unroll
      for (int j = 0; j < 32; j += 2) {
        double2 cv = *(const double2*)(cp + j); // broadcast (uniform addr) LDS read
        s += xd[j] * cv.x;
        s += xd[j + 1] * cv.y;
      }
      dot[k] = s;
    }
  }

  int a = 0;
  double best = csq_lds[0] - 2.0 * (dot[0] * inv);
#pragma unroll
  for (int k = 1; k < NSLOT; ++k) {
    double s = csq_lds[k] - 2.0 * (dot[k] * inv);
    if (s < best) { best = s; a = k; } // strict < keeps first occurrence (jnp/np argmin)
  }

  if (final_pass) {
    // slot_masks[b][k][n]
#pragma unroll
    for (int k = 0; k < NSLOT; ++k)
      masks_out[((size_t)b * NSLOT + k) * NPTS + n] = (k == a) ? 1.0f : 0.0f;
    if (ch == 0) {
#pragma unroll
      for (int i = 0; i < NSLOT; ++i)
        centers_out[((size_t)b * NSLOT + i) * DIM + t] = (float)cb[i * DIM + t];
    }
    return;
  }

  assign_lds[t] = a;
  __syncthreads();

  // ---- phase 2: thread-per-dim partial sums (deterministic fixed order) ----
  double acc[NSLOT];
  int cnt[NSLOT];
#pragma unroll
  for (int k = 0; k < NSLOT; ++k) { acc[k] = 0.0; cnt[k] = 0; }

  const float* fb = feat + ((size_t)b * NPTS + ch * PTS) * DIM + t;
  const double* ib = inv_norm + b * NPTS + ch * PTS;
  for (int p = 0; p < PTS; ++p) {
    int a_s = __builtin_amdgcn_readfirstlane(assign_lds[p]); // block-uniform
    double xv = (double)fb[(size_t)p * DIM] * ib[p];
    switch (a_s) {
      CASE_ACC(0) CASE_ACC(1) CASE_ACC(2) CASE_ACC(3)
      CASE_ACC(4) CASE_ACC(5) CASE_ACC(6) CASE_ACC(7)
      CASE_ACC(8) CASE_ACC(9) CASE_ACC(10) CASE_ACC(11)
      CASE_ACC(12) CASE_ACC(13) CASE_ACC(14) CASE_ACC(15)
      CASE_ACC(16) CASE_ACC(17) CASE_ACC(18) CASE_ACC(19)
      CASE_ACC(20) CASE_ACC(21) CASE_ACC(22) CASE_ACC(23)
    }
  }

  double* ps = psums + ((size_t)(b * NCHUNK + ch) * NSLOT) * DIM + t;
#pragma unroll
  for (int k = 0; k < NSLOT; ++k) ps[(size_t)k * DIM] = acc[k];
  if (t == 0) {
    int* pc = pcnts + (b * NCHUNK + ch) * NSLOT;
#pragma unroll
    for (int k = 0; k < NSLOT; ++k) pc[k] = cnt[k];
  }
}

// ---------------- K2: reduce partials -> new centers + c_sq ----------------
__global__ __launch_bounds__(256) void k_update(const double* __restrict__ psums,
                                                const int* __restrict__ pcnts,
                                                double* __restrict__ centers,
                                                double* __restrict__ c_sq) {
  __shared__ double red[4];
  int t = threadIdx.x, k = blockIdx.x, b = blockIdx.y;
  double s = 0.0;
#pragma unroll
  for (int ch = 0; ch < NCHUNK; ++ch)
    s += psums[((size_t)(b * NCHUNK + ch) * NSLOT + k) * DIM + t];
  int cnt = 0;
#pragma unroll
  for (int ch = 0; ch < NCHUNK; ++ch)
    cnt += pcnts[(b * NCHUNK + ch) * NSLOT + k];
  size_t ci = ((size_t)b * NSLOT + k) * DIM + t;
  double nc = (cnt > 0) ? (s / (double)cnt) : centers[ci]; // where(counts>0, sums/max(counts,1), old)
  centers[ci] = nc;
  double sq = block_sum_256(nc * nc, red);
  if (t == 0) c_sq[b * NSLOT + k] = sq;
}

extern "C" void kernel_launch(void* const* d_in, const int* in_sizes, int n_in,
                              void* d_out, int out_size, void* d_ws, size_t ws_size,
                              hipStream_t stream) {
  (void)in_sizes; (void)n_in; (void)out_size; (void)ws_size;
  const float* feat = (const float*)d_in[0];
  float* out_centers = (float*)d_out;                                  // (32,24,256)
  float* out_masks = out_centers + (size_t)BATCH * NSLOT * DIM;        // (32,24,4096)

  // workspace layout (~27.8 MB total)
  char* ws = (char*)d_ws;
  double* inv_norm = (double*)ws;  ws += (size_t)BATCH * NPTS * 8;                  // 1.0 MB
  double* centers  = (double*)ws;  ws += (size_t)BATCH * NSLOT * DIM * 8;           // 1.5 MB
  double* c_sq     = (double*)ws;  ws += (size_t)BATCH * NSLOT * 8;                 // 6 KB
  double* psums    = (double*)ws;  ws += (size_t)BATCH * NCHUNK * NSLOT * DIM * 8;  // 25 MB
  int* pcnts       = (int*)ws;                                                       // 48 KB

  k_norm<<<BATCH * NPTS / 4, 256, 0, stream>>>(feat, inv_norm);
  k_init_centers<<<dim3(NSLOT, BATCH), 256, 0, stream>>>(feat, inv_norm, centers, c_sq);
  for (int it = 0; it < NITER; ++it) {
    k_iter<<<dim3(NCHUNK, BATCH), 256, 0, stream>>>(feat, inv_norm, centers, c_sq,
                                                    psums, pcnts, nullptr, nullptr, 0);
    k_update<<<dim3(NSLOT, BATCH), 256, 0, stream>>>(psums, pcnts, centers, c_sq);
  }
  k_iter<<<dim3(NCHUNK, BATCH), 256, 0, stream>>>(feat, inv_norm, centers, c_sq,
                                                  psums, pcnts, out_masks, out_centers, 1);
}